// Round 4
// baseline (3925.743 us; speedup 1.0000x reference)
//
#include <hip/hip_runtime.h>
#include <hip/hip_bf16.h>
#include <math.h>

typedef __bf16 bf16x8 __attribute__((ext_vector_type(8)));
typedef float floatx4 __attribute__((ext_vector_type(4)));

#define T_LEN 128

// ws layout: bf16 fragment-packed weights, gates KI-MAJOR:
// gate frag addr = WP_OFF + ki*65536 + ct*1024 + lane*16
// K-order REMAPPED: [ z(32) | a(8) | h(256) | pad(24) ]  (ki=0 is pure z)
#define WP_OFF   0
#define WP_SZ    (64*10*64*16)     // 655360
#define W1P_OFF  (WP_OFF + WP_SZ)
#define W1P_SZ   (8*8*64*16)       // 65536
#define W2P_OFF  (W1P_OFF + W1P_SZ)
#define W2P_SZ   (8*4*64*16)       // 32768
#define WZP_OFF  (W2P_OFF + W2P_SZ)
#define WZP_SZ   (4*4*64*16)       // 16384
#define WS_NEEDED ((size_t)(WZP_OFF + WZP_SZ))   // 770048 B

// ---- fast transcendentals ------------------------------------------------
#if __has_builtin(__builtin_amdgcn_exp2f)
#define EXP2F(x) __builtin_amdgcn_exp2f(x)
#else
#define EXP2F(x) exp2f(x)
#endif
#if __has_builtin(__builtin_amdgcn_logf)
#define LOG2F(x) __builtin_amdgcn_logf(x)
#else
#define LOG2F(x) log2f(x)
#endif
#if __has_builtin(__builtin_amdgcn_rcpf)
#define RCPF(x) __builtin_amdgcn_rcpf(x)
#else
#define RCPF(x) (1.0f/(x))
#endif

__device__ __forceinline__ float fsigmoid(float x) {
    return RCPF(1.0f + EXP2F(-1.4426950408889634f * x));
}
__device__ __forceinline__ float ftanh(float x) {
    return 1.0f - 2.0f * RCPF(1.0f + EXP2F(2.8853900817779268f * x));
}

// ---------------- prep: f32 weights -> bf16 B-fragment-linear in ws -------
// Gate K-columns remapped: k<32 -> z (Wih col 8+k); 32<=k<40 -> a (Wih col
// k-32); 40<=k<296 -> h (Whh col k-40); else 0.
__global__ void prep_kernel(const float* __restrict__ Wih, const float* __restrict__ Whh,
                            const float* __restrict__ W1,  const float* __restrict__ W2,
                            const float* __restrict__ Wz,  unsigned char* __restrict__ ws)
{
    int id = blockIdx.x * blockDim.x + threadIdx.x;
    __bf16* Wp  = (__bf16*)(ws + WP_OFF);
    __bf16* W1p = (__bf16*)(ws + W1P_OFF);
    __bf16* W2p = (__bf16*)(ws + W2P_OFF);
    __bf16* Wzp = (__bf16*)(ws + WZP_OFF);
    if (id < 40960) {                       // gates: 64 ct x 10 ki x 64 lanes
        int ct = id / 640, rem = id % 640;
        int ki = rem / 64, lane = rem % 64;
        int row = ct * 16 + (lane & 15);                 // gate-output col
        int kb  = ki * 32 + (lane >> 4) * 8;
        for (int j = 0; j < 8; ++j) {
            int k = kb + j;
            float v;
            if (k < 32)       v = Wih[row * 40 + 8 + k];        // z block
            else if (k < 40)  v = Wih[row * 40 + (k - 32)];     // a block
            else if (k < 296) v = Whh[row * 256 + (k - 40)];    // h block
            else              v = 0.0f;                          // pad
            Wp[((size_t)(ki * 64 + ct) * 64 + lane) * 8 + j] = (__bf16)v;
        }
    } else if (id < 45056) {                // W1: 8 ct x 8 ki (ct-major)
        int id2 = id - 40960;
        int rem = id2 % 512, lane = rem % 64;
        int row = (id2 / 512) * 16 + (lane & 15);
        int kb  = (rem / 64) * 32 + (lane >> 4) * 8;
        for (int j = 0; j < 8; ++j) W1p[(size_t)id2 * 8 + j] = (__bf16)W1[row * 256 + kb + j];
    } else if (id < 47104) {                // W2: 8 ct x 4 ki
        int id3 = id - 45056;
        int rem = id3 % 256, lane = rem % 64;
        int row = (id3 / 256) * 16 + (lane & 15);
        int kb  = (rem / 64) * 32 + (lane >> 4) * 8;
        for (int j = 0; j < 8; ++j) W2p[(size_t)id3 * 8 + j] = (__bf16)W2[row * 128 + kb + j];
    } else if (id < 48128) {                // Wz: 4 ct x 4 ki
        int id4 = id - 47104;
        int rem = id4 % 256, lane = rem % 64;
        int row = (id4 / 256) * 16 + (lane & 15);
        int kb  = (rem / 64) * 32 + (lane >> 4) * 8;
        for (int j = 0; j < 8; ++j) Wzp[(size_t)id4 * 8 + j] = (__bf16)Wz[row * 128 + kb + j];
    }
}

// ---------------- fast path: 64 blocks x 576 threads (9 waves) ------------
// R10: 2 barriers/step, gates off the critical path.
//  Wave 0:    full MLP chain u1->u2->zz->z in ONE wave (same-wave LDS
//             relayout, no barriers); MLP weights LDS-resident.
//  Waves 1-8: gates (8 ct each) + cell. h-part of gates(t+1) (ki=1..9)
//             computed DURING wave 0's MLP(t). z-part = ki=0 only.
//  Weight stream: circular 20-group register double-buffer (bufA/bufB),
//  t-invariant addresses; z-groups (18,19) load a full interval ahead.
// xh col layout: [ z(0..31) | a(32..39) | h(40..295) | pad ]
__global__ __launch_bounds__(576)
__attribute__((amdgpu_waves_per_eu(3)))
void seq_mfma(
    const float* __restrict__ A,   const float* __restrict__ eps,
    const float* __restrict__ z0,  const float* __restrict__ h0,
    const float* __restrict__ c0,
    const float* __restrict__ bih, const float* __restrict__ bhh,
    const float* __restrict__ b1,  const float* __restrict__ b2,
    const float* __restrict__ bz,
    const unsigned char* __restrict__ ws, float* __restrict__ out)
{
    const int tid  = threadIdx.x;
    const int wave = tid >> 6;
    const int lane = tid & 63;
    const int lrow = lane & 15;
    const int quad = lane >> 4;
    const int n0   = blockIdx.x * 16;
    const int w1   = (wave > 0) ? wave - 1 : 0;   // gate-wave index 0..7

    __shared__ __align__(16) __bf16 wmlp[(W1P_SZ + W2P_SZ + WZP_SZ) / 2];
    __shared__ __align__(16) __bf16 xh[2][16][328];
    __shared__ __align__(16) __bf16 scr1[16][136];
    __shared__ __align__(16) __bf16 scr2[16][136];

    {   // one-time: MLP weights global -> LDS (7168 x 16B)
        const float4* src = (const float4*)(ws + W1P_OFF);
        float4* dst = (float4*)wmlp;
        for (int i = tid; i < 7168; i += 576) dst[i] = src[i];
    }
    const __bf16* w1l = wmlp;                  // ct*4096 + ki*512 + lane*8
    const __bf16* w2l = wmlp + 32768;          // ct*2048 + ki*512 + lane*8
    const __bf16* wzl = wmlp + 32768 + 16384;  // ct*2048 + ki*512 + lane*8

    // init both xh buffers: z0 | 0(a) | h0 | zero pad
    for (int idx = tid; idx < 2 * 16 * 320; idx += 576) {
        int b = idx / (16 * 320);
        int rem = idx % (16 * 320);
        int r = rem / 320, col = rem % 320;
        float v;
        if (col < 32)                     v = z0[col];
        else if (col >= 40 && col < 296)  v = h0[col - 40];
        else                              v = 0.0f;
        xh[b][r][col] = (__bf16)v;
    }
    if (tid < 128)   // a(t=0)
        xh[0][tid >> 3][32 + (tid & 7)] =
            (__bf16)A[((size_t)(n0 + (tid >> 3)) * T_LEN + 0) * 8 + (tid & 7)];

    __syncthreads();

    // -------- persistent per-wave state --------
    // gate waves:
    const char* wsg = (const char*)ws + WP_OFF + (size_t)(2 * w1) * 1024 + (size_t)lane * 16;
    bf16x8 bufA[4], bufB[4];
    floatx4 acc[4][2];
    float gb[4][2], cst[2][4];
    // wave 0:
    float b1r[8], b2r[8], bzL[2], bzR[2], zvp[8];

    if (wave == 0) {
        #pragma unroll
        for (int c = 0; c < 8; ++c) { b1r[c] = b1[c * 16 + lrow]; b2r[c] = b2[c * 16 + lrow]; }
        #pragma unroll
        for (int c = 0; c < 2; ++c) { bzL[c] = bz[c * 16 + lrow]; bzR[c] = bz[32 + c * 16 + lrow]; }
        #pragma unroll
        for (int i = 0; i < 8; ++i) zvp[i] = 0.0f;
    } else {
        #pragma unroll
        for (int g = 0; g < 4; ++g)
            #pragma unroll
            for (int j = 0; j < 2; ++j) {
                int unit = 32 * w1 + 16 * j + lrow;
                gb[g][j] = bih[g * 256 + unit] + bhh[g * 256 + unit];
            }
        #pragma unroll
        for (int j = 0; j < 2; ++j) {
            float cv = c0[32 * w1 + 16 * j + lrow];
            #pragma unroll
            for (int r = 0; r < 4; ++r) cst[j][r] = cv;
        }
        // -------- prologue: acc = bias + gates-h(0) from h0 (depth-1) -----
        #pragma unroll
        for (int g = 0; g < 4; ++g)
            #pragma unroll
            for (int j = 0; j < 2; ++j)
                acc[g][j] = (floatx4){gb[g][j], gb[g][j], gb[g][j], gb[g][j]};
        #pragma unroll
        for (int gi = 0; gi < 18; ++gi) {
            const int ki = 1 + (gi >> 1), j = gi & 1;
            bf16x8 af = *(const bf16x8*)&xh[0][lrow][ki * 32 + quad * 8];
            #pragma unroll
            for (int g = 0; g < 4; ++g) {
                bf16x8 b = *(const bf16x8*)(wsg + ki * 65536 + j * 1024 + g * 16384);
                acc[g][j] = __builtin_amdgcn_mfma_f32_16x16x32_bf16(af, b, acc[g][j], 0, 0, 0);
            }
        }
        // preload z-groups (ki=0, j=0/1)
        #pragma unroll
        for (int g = 0; g < 4; ++g) {
            bufA[g] = *(const bf16x8*)(wsg + g * 16384);
            bufB[g] = *(const bf16x8*)(wsg + 1024 + g * 16384);
        }
    }

    for (int t = 0; t < T_LEN; ++t) {
        const int cb = t & 1;        // X_t
        const int nb = cb ^ 1;       // X_{t+1}
        float epsr[8];

        // ================= interval 1 =================
        if (wave == 0) {
            // deferred out-store of z(t-1); then issue eps(t) loads
            if (t > 0) {
                #pragma unroll
                for (int c = 0; c < 2; ++c)
                    #pragma unroll
                    for (int r = 0; r < 4; ++r)
                        out[((size_t)(n0 + quad * 4 + r) * T_LEN + (t - 1)) * 32 + c * 16 + lrow]
                            = zvp[c * 4 + r];
            }
            #pragma unroll
            for (int c = 0; c < 2; ++c)
                #pragma unroll
                for (int r = 0; r < 4; ++r)
                    epsr[c * 4 + r] =
                        eps[((size_t)(n0 + quad * 4 + r) * T_LEN + t) * 32 + c * 16 + lrow];
        } else {
            const int atid = tid - 64;    // waves 1-2 stage a
            float a_nxt = 0.0f;
            if (atid < 128 && t + 1 < T_LEN)
                a_nxt = A[((size_t)(n0 + (atid >> 3)) * T_LEN + (t + 1)) * 8 + (atid & 7)];

            // gates-z: ki=0 (z_t cols 0..31)
            bf16x8 af0 = *(const bf16x8*)&xh[cb][lrow][quad * 8];
            #pragma unroll
            for (int g = 0; g < 4; ++g) {
                acc[g][0] = __builtin_amdgcn_mfma_f32_16x16x32_bf16(af0, bufA[g], acc[g][0], 0, 0, 0);
                acc[g][1] = __builtin_amdgcn_mfma_f32_16x16x32_bf16(af0, bufB[g], acc[g][1], 0, 0, 0);
            }
            // reload groups 0,1 (ki=1) — consumed at interval-2 start
            #pragma unroll
            for (int g = 0; g < 4; ++g) {
                bufA[g] = *(const bf16x8*)(wsg + 65536 + g * 16384);
                bufB[g] = *(const bf16x8*)(wsg + 65536 + 1024 + g * 16384);
            }
            // LSTM cell -> h_{t+1} into X_{t+1}
            #pragma unroll
            for (int j = 0; j < 2; ++j)
                #pragma unroll
                for (int r = 0; r < 4; ++r) {
                    float iv = fsigmoid(acc[0][j][r]);
                    float fv = fsigmoid(acc[1][j][r]);
                    float gv = ftanh(acc[2][j][r]);
                    float ov = fsigmoid(acc[3][j][r]);
                    float cn = fv * cst[j][r] + iv * gv;
                    cst[j][r] = cn;
                    xh[nb][quad * 4 + r][40 + 32 * w1 + 16 * j + lrow] = (__bf16)(ov * ftanh(cn));
                }
            if (atid < 128 && t + 1 < T_LEN)
                xh[nb][atid >> 3][32 + (atid & 7)] = (__bf16)a_nxt;
        }
        __syncthreads();   // B2: h_{t+1} + a_{t+1} staged in X_{t+1}

        // ================= interval 2 =================
        if (wave == 0) {
            // ---- u1 = relu(h @ W1^T + b1) : 8 ct x 8 ki, M=16
            floatx4 a1[8];
            #pragma unroll
            for (int c = 0; c < 8; ++c)
                a1[c] = (floatx4){b1r[c], b1r[c], b1r[c], b1r[c]};
            #pragma unroll
            for (int ki = 0; ki < 8; ++ki) {
                bf16x8 af = *(const bf16x8*)&xh[nb][lrow][40 + ki * 32 + quad * 8];
                #pragma unroll
                for (int c = 0; c < 8; ++c) {
                    bf16x8 b = *(const bf16x8*)&w1l[c * 4096 + ki * 512 + lane * 8];
                    a1[c] = __builtin_amdgcn_mfma_f32_16x16x32_bf16(af, b, a1[c], 0, 0, 0);
                }
            }
            // relayout C->A (same-wave LDS round-trip, no barrier)
            #pragma unroll
            for (int c = 0; c < 8; ++c)
                #pragma unroll
                for (int r = 0; r < 4; ++r)
                    scr1[quad * 4 + r][c * 16 + lrow] = (__bf16)fmaxf(a1[c][r], 0.0f);
            // ---- u2 = relu(u1 @ W2^T + b2) : 8 ct x 4 ki
            floatx4 a2[8];
            #pragma unroll
            for (int c = 0; c < 8; ++c)
                a2[c] = (floatx4){b2r[c], b2r[c], b2r[c], b2r[c]};
            #pragma unroll
            for (int ki = 0; ki < 4; ++ki) {
                bf16x8 af = *(const bf16x8*)&scr1[lrow][ki * 32 + quad * 8];
                #pragma unroll
                for (int c = 0; c < 8; ++c) {
                    bf16x8 b = *(const bf16x8*)&w2l[c * 2048 + ki * 512 + lane * 8];
                    a2[c] = __builtin_amdgcn_mfma_f32_16x16x32_bf16(af, b, a2[c], 0, 0, 0);
                }
            }
            #pragma unroll
            for (int c = 0; c < 8; ++c)
                #pragma unroll
                for (int r = 0; r < 4; ++r)
                    scr2[quad * 4 + r][c * 16 + lrow] = (__bf16)fmaxf(a2[c][r], 0.0f);
            // ---- zz: loc ct 0,1 / raw ct 2,3
            floatx4 aL[2], aR[2];
            #pragma unroll
            for (int c = 0; c < 2; ++c) {
                aL[c] = (floatx4){bzL[c], bzL[c], bzL[c], bzL[c]};
                aR[c] = (floatx4){bzR[c], bzR[c], bzR[c], bzR[c]};
            }
            #pragma unroll
            for (int ki = 0; ki < 4; ++ki) {
                bf16x8 af = *(const bf16x8*)&scr2[lrow][ki * 32 + quad * 8];
                #pragma unroll
                for (int c = 0; c < 2; ++c) {
                    bf16x8 bl = *(const bf16x8*)&wzl[(c)     * 2048 + ki * 512 + lane * 8];
                    bf16x8 br = *(const bf16x8*)&wzl[(c + 2) * 2048 + ki * 512 + lane * 8];
                    aL[c] = __builtin_amdgcn_mfma_f32_16x16x32_bf16(af, bl, aL[c], 0, 0, 0);
                    aR[c] = __builtin_amdgcn_mfma_f32_16x16x32_bf16(af, br, aR[c], 0, 0, 0);
                }
            }
            // ---- z = loc + softplus(raw)*eps -> X_{t+1}.z ; out deferred
            #pragma unroll
            for (int c = 0; c < 2; ++c)
                #pragma unroll
                for (int r = 0; r < 4; ++r) {
                    float raw = aR[c][r];
                    float sp  = (raw > 20.0f)
                              ? raw
                              : 0.6931471805599453f *
                                LOG2F(1.0f + EXP2F(1.4426950408889634f * raw));
                    float zv  = aL[c][r] + sp * epsr[c * 4 + r];
                    zvp[c * 4 + r] = zv;
                    xh[nb][quad * 4 + r][c * 16 + lrow] = (__bf16)zv;
                }
        } else if (t + 1 < T_LEN) {
            // gates-h(t+1): circular 20-group pipeline (groups 0..17 = h)
            #pragma unroll
            for (int g = 0; g < 4; ++g)
                #pragma unroll
                for (int j = 0; j < 2; ++j)
                    acc[g][j] = (floatx4){gb[g][j], gb[g][j], gb[g][j], gb[g][j]};
            bf16x8 af;
            #pragma unroll
            for (int gi = 0; gi < 18; ++gi) {
                const int ki = 1 + (gi >> 1);
                if ((gi & 1) == 0) {
                    af = *(const bf16x8*)&xh[nb][lrow][ki * 32 + quad * 8];
                    #pragma unroll
                    for (int g = 0; g < 4; ++g)
                        acc[g][0] = __builtin_amdgcn_mfma_f32_16x16x32_bf16(af, bufA[g], acc[g][0], 0, 0, 0);
                    const int ng  = gi + 2;                       // next group for this slot
                    const int nki = (ng < 18) ? 1 + (ng >> 1) : 0;
                    const int nj  = (ng < 18) ? (ng & 1) : 0;     // 18 -> (0,0)
                    #pragma unroll
                    for (int g = 0; g < 4; ++g)
                        bufA[g] = *(const bf16x8*)(wsg + nki * 65536 + nj * 1024 + g * 16384);
                } else {
                    #pragma unroll
                    for (int g = 0; g < 4; ++g)
                        acc[g][1] = __builtin_amdgcn_mfma_f32_16x16x32_bf16(af, bufB[g], acc[g][1], 0, 0, 0);
                    const int ng  = gi + 2;
                    const int nki = (ng < 18) ? 1 + (ng >> 1) : 0;
                    const int nj  = (ng < 18) ? (ng & 1) : 1;     // 19 -> (0,1)
                    #pragma unroll
                    for (int g = 0; g < 4; ++g)
                        bufB[g] = *(const bf16x8*)(wsg + nki * 65536 + nj * 1024 + g * 16384);
                }
            }
        }
        __syncthreads();   // B1: z_t staged in X_{t+1}
    }

    // flush z(127) out-stores
    if (wave == 0) {
        #pragma unroll
        for (int c = 0; c < 2; ++c)
            #pragma unroll
            for (int r = 0; r < 4; ++r)
                out[((size_t)(n0 + quad * 4 + r) * T_LEN + (T_LEN - 1)) * 32 + c * 16 + lrow]
                    = zvp[c * 4 + r];
    }
}

// ---------------- fallback: proven R4 VALU kernel (f32 hard-coded) --------
struct SM {
    float zx[4][40]; float h[4][256]; float u1[4][128]; float u2[4][128]; float zz[4][64];
};

__global__ __launch_bounds__(256) void seq_valu(
    const float* __restrict__ A, const float* __restrict__ eps,
    const float* __restrict__ z0, const float* __restrict__ h0, const float* __restrict__ c0,
    const float* __restrict__ Wih, const float* __restrict__ Whh,
    const float* __restrict__ bih, const float* __restrict__ bhh,
    const float* __restrict__ W1, const float* __restrict__ b1,
    const float* __restrict__ W2, const float* __restrict__ b2,
    const float* __restrict__ Wz, const float* __restrict__ bz, float* __restrict__ out)
{
    __shared__ SM sm;
    const int tid = threadIdx.x;
    const int n0  = blockIdx.x * 4;
    if (tid < 128) { int rr = tid >> 5, cc = tid & 31; sm.zx[rr][8 + cc] = z0[cc]; }
    for (int i = tid; i < 4 * 256; i += 256) sm.h[i >> 8][i & 255] = h0[i & 255];
    float c[4];
    #pragma unroll
    for (int rr = 0; rr < 4; ++rr) c[rr] = c0[tid];
    float gbias[4];
    #pragma unroll
    for (int g = 0; g < 4; ++g) gbias[g] = bih[g * 256 + tid] + bhh[g * 256 + tid];

    for (int t = 0; t < T_LEN; ++t) {
        if (tid < 32) { int rr = tid >> 3, cc = tid & 7;
            sm.zx[rr][cc] = A[((size_t)(n0 + rr) * T_LEN + t) * 8 + cc]; }
        __syncthreads();
        float acc[4][4];
        #pragma unroll
        for (int g = 0; g < 4; ++g)
            #pragma unroll
            for (int rr = 0; rr < 4; ++rr) acc[g][rr] = gbias[g];
        for (int k = 0; k < 40; ++k) {
            float xv[4];
            #pragma unroll
            for (int rr = 0; rr < 4; ++rr) xv[rr] = sm.zx[rr][k];
            #pragma unroll
            for (int g = 0; g < 4; ++g) {
                float w = Wih[(size_t)(g * 256 + tid) * 40 + k];
                #pragma unroll
                for (int rr = 0; rr < 4; ++rr) acc[g][rr] += w * xv[rr];
            }
        }
        for (int k = 0; k < 256; ++k) {
            float hv[4];
            #pragma unroll
            for (int rr = 0; rr < 4; ++rr) hv[rr] = sm.h[rr][k];
            #pragma unroll
            for (int g = 0; g < 4; ++g) {
                float w = Whh[(size_t)(g * 256 + tid) * 256 + k];
                #pragma unroll
                for (int rr = 0; rr < 4; ++rr) acc[g][rr] += w * hv[rr];
            }
        }
        __syncthreads();
        #pragma unroll
        for (int rr = 0; rr < 4; ++rr) {
            float iv = 1.0f / (1.0f + expf(-acc[0][rr]));
            float fv = 1.0f / (1.0f + expf(-acc[1][rr]));
            float gv = tanhf(acc[2][rr]);
            float ov = 1.0f / (1.0f + expf(-acc[3][rr]));
            float cn = fv * c[rr] + iv * gv;
            c[rr] = cn;
            sm.h[rr][tid] = ov * tanhf(cn);
        }
        __syncthreads();
        { int col = tid & 127, rb = (tid >> 7) * 2;
          float a0 = b1[col], a1 = a0;
          for (int k = 0; k < 256; ++k) { float w = W1[(size_t)col * 256 + k];
              a0 += w * sm.h[rb][k]; a1 += w * sm.h[rb + 1][k]; }
          sm.u1[rb][col] = fmaxf(a0, 0.0f); sm.u1[rb + 1][col] = fmaxf(a1, 0.0f); }
        __syncthreads();
        { int col = tid & 127, rb = (tid >> 7) * 2;
          float a0 = b2[col], a1 = a0;
          for (int k = 0; k < 128; ++k) { float w = W2[(size_t)col * 128 + k];
              a0 += w * sm.u1[rb][k]; a1 += w * sm.u1[rb + 1][k]; }
          sm.u2[rb][col] = fmaxf(a0, 0.0f); sm.u2[rb + 1][col] = fmaxf(a1, 0.0f); }
        __syncthreads();
        { int rr = tid >> 6, col = tid & 63;
          float a0 = bz[col];
          for (int k = 0; k < 128; ++k) a0 += Wz[(size_t)col * 128 + k] * sm.u2[rr][k];
          sm.zz[rr][col] = a0; }
        __syncthreads();
        if (tid < 128) {
            int rr = tid >> 5, cc = tid & 31;
            float loc = sm.zz[rr][cc], raw = sm.zz[rr][cc + 32];
            float sp  = (raw > 20.0f) ? raw : log1pf(expf(raw));
            float ev  = eps[((size_t)(n0 + rr) * T_LEN + t) * 32 + cc];
            float zv  = loc + sp * ev;
            sm.zx[rr][8 + cc] = zv;
            out[((size_t)(n0 + rr) * T_LEN + t) * 32 + cc] = zv;
        }
        __syncthreads();
    }
}

extern "C" void kernel_launch(void* const* d_in, const int* in_sizes, int n_in,
                              void* d_out, int out_size, void* d_ws, size_t ws_size,
                              hipStream_t stream)
{
    const float* A   = (const float*)d_in[0];
    const float* eps = (const float*)d_in[1];
    const float* z0  = (const float*)d_in[2];
    const float* h0  = (const float*)d_in[3];
    const float* c0  = (const float*)d_in[4];
    const float* Wih = (const float*)d_in[5];
    const float* Whh = (const float*)d_in[6];
    const float* bih = (const float*)d_in[7];
    const float* bhh = (const float*)d_in[8];
    const float* W1  = (const float*)d_in[9];
    const float* b1  = (const float*)d_in[10];
    const float* W2  = (const float*)d_in[11];
    const float* b2  = (const float*)d_in[12];
    const float* Wz  = (const float*)d_in[13];
    const float* bz  = (const float*)d_in[14];
    float* out = (float*)d_out;

    if (ws_size >= WS_NEEDED) {
        prep_kernel<<<188, 256, 0, stream>>>(Wih, Whh, W1, W2, Wz, (unsigned char*)d_ws);
        seq_mfma<<<64, 576, 0, stream>>>(A, eps, z0, h0, c0,
                                         bih, bhh, b1, b2, bz,
                                         (const unsigned char*)d_ws, out);
    } else {
        seq_valu<<<256, 256, 0, stream>>>(A, eps, z0, h0, c0, Wih, Whh, bih, bhh,
                                          W1, b1, W2, b2, Wz, bz, out);
    }
}

// Round 5
// 2191.191 us; speedup vs baseline: 1.7916x; 1.7916x over previous
//
#include <hip/hip_runtime.h>
#include <hip/hip_bf16.h>
#include <math.h>

typedef __bf16 bf16x8 __attribute__((ext_vector_type(8)));
typedef float floatx4 __attribute__((ext_vector_type(4)));

#define T_LEN 128

// ws layout: bf16 fragment-packed weights, gates KI-MAJOR:
//   gate frag addr = WP_OFF + ki*65536 + ct*1024 + lane*16
// K order: [ a(8) | z(32) | h(256) | pad(24) ]  (R1's proven xh layout)
#define WP_OFF   0
#define WP_SZ    (64*10*64*16)     // 655360
#define W1P_OFF  (WP_OFF + WP_SZ)
#define W1P_SZ   (8*8*64*16)       // 65536
#define W2P_OFF  (W1P_OFF + W1P_SZ)
#define W2P_SZ   (8*4*64*16)       // 32768
#define WZP_OFF  (W2P_OFF + W2P_SZ)
#define WZP_SZ   (4*4*64*16)       // 16384
#define WS_NEEDED ((size_t)(WZP_OFF + WZP_SZ))   // 770048 B

// ---- fast transcendentals ------------------------------------------------
#if __has_builtin(__builtin_amdgcn_exp2f)
#define EXP2F(x) __builtin_amdgcn_exp2f(x)
#else
#define EXP2F(x) exp2f(x)
#endif
#if __has_builtin(__builtin_amdgcn_logf)
#define LOG2F(x) __builtin_amdgcn_logf(x)
#else
#define LOG2F(x) log2f(x)
#endif
#if __has_builtin(__builtin_amdgcn_rcpf)
#define RCPF(x) __builtin_amdgcn_rcpf(x)
#else
#define RCPF(x) (1.0f/(x))
#endif

__device__ __forceinline__ float fsigmoid(float x) {
    return RCPF(1.0f + EXP2F(-1.4426950408889634f * x));
}
__device__ __forceinline__ float ftanh(float x) {
    return 1.0f - 2.0f * RCPF(1.0f + EXP2F(2.8853900817779268f * x));
}

// ---------------- prep: f32 weights -> bf16 B-fragment-linear in ws -------
__global__ void prep_kernel(const float* __restrict__ Wih, const float* __restrict__ Whh,
                            const float* __restrict__ W1,  const float* __restrict__ W2,
                            const float* __restrict__ Wz,  unsigned char* __restrict__ ws)
{
    int id = blockIdx.x * blockDim.x + threadIdx.x;
    __bf16* Wp  = (__bf16*)(ws + WP_OFF);
    __bf16* W1p = (__bf16*)(ws + W1P_OFF);
    __bf16* W2p = (__bf16*)(ws + W2P_OFF);
    __bf16* Wzp = (__bf16*)(ws + WZP_OFF);
    if (id < 40960) {                       // gates: 64 ct x 10 ki x 64 lanes
        int ct = id / 640, rem = id % 640;
        int ki = rem / 64, lane = rem % 64;
        int row = ct * 16 + (lane & 15);                 // gate-output col
        int kb  = ki * 32 + (lane >> 4) * 8;
        for (int j = 0; j < 8; ++j) {
            int k = kb + j;
            float v;
            if (k < 40)       v = Wih[row * 40 + k];     // [a|z] = Wih cols
            else if (k < 296) v = Whh[row * 256 + (k - 40)];
            else              v = 0.0f;                   // pad 296..319
            Wp[((size_t)(ki * 64 + ct) * 64 + lane) * 8 + j] = (__bf16)v;
        }
    } else if (id < 45056) {                // W1: 8 ct x 8 ki (ct-major)
        int id2 = id - 40960;
        int rem = id2 % 512, lane = rem % 64;
        int row = (id2 / 512) * 16 + (lane & 15);
        int kb  = (rem / 64) * 32 + (lane >> 4) * 8;
        for (int j = 0; j < 8; ++j) W1p[(size_t)id2 * 8 + j] = (__bf16)W1[row * 256 + kb + j];
    } else if (id < 47104) {                // W2: 8 ct x 4 ki
        int id3 = id - 45056;
        int rem = id3 % 256, lane = rem % 64;
        int row = (id3 / 256) * 16 + (lane & 15);
        int kb  = (rem / 64) * 32 + (lane >> 4) * 8;
        for (int j = 0; j < 8; ++j) W2p[(size_t)id3 * 8 + j] = (__bf16)W2[row * 128 + kb + j];
    } else if (id < 48128) {                // Wz: 4 ct x 4 ki
        int id4 = id - 47104;
        int rem = id4 % 256, lane = rem % 64;
        int row = (id4 / 256) * 16 + (lane & 15);
        int kb  = (rem / 64) * 32 + (lane >> 4) * 8;
        for (int j = 0; j < 8; ++j) Wzp[(size_t)id4 * 8 + j] = (__bf16)Wz[row * 128 + kb + j];
    }
}

// ---------------- fast path: 64 blocks x 512 threads (8 waves) ------------
// R5: per-CU ingress reduction via residency (2 waves/SIMD -> 256 VGPR cap).
//   VGPR-resident: gate ki0,ki1 (64 regs) + W1 frags (32 regs).
//   LDS-resident:  gate ki2,ki3 (128 KB).
//   Streamed/step: gate ki4..9 (384 KB) + W2 (32 KB) + Wz (16 KB).
// Wave w owns gate ct = g*16 + 2w + j (unit cols [32w, 32w+32)), u1/u2 ct=w,
// zz ct=w for w<4 (loc ct 0,1; raw ct 2,3). 5 barriers/step (R1 skeleton).
__global__ __launch_bounds__(512) void seq_mfma(
    const float* __restrict__ A,   const float* __restrict__ eps,
    const float* __restrict__ z0,  const float* __restrict__ h0,
    const float* __restrict__ c0,
    const float* __restrict__ bih, const float* __restrict__ bhh,
    const float* __restrict__ b1,  const float* __restrict__ b2,
    const float* __restrict__ bz,
    const unsigned char* __restrict__ ws, float* __restrict__ out)
{
    const int tid  = threadIdx.x;
    const int w    = tid >> 6;          // wave 0..7
    const int lane = tid & 63;
    const int lrow = lane & 15;
    const int quad = lane >> 4;
    const int n0   = blockIdx.x * 16;

    __shared__ __align__(16) __bf16 slab23[2][32768];  // gate ki2, ki3 (128 KB)
    __shared__ __align__(16) __bf16 xh[2][16][328];    // [a(8)|z(32)|h(256)|pad]
    __shared__ __align__(16) __bf16 u1s[16][136];      // also zz f32 overlay
    __shared__ __align__(16) __bf16 u2s[16][136];
    float* zzf = (float*)&u1s[0][0];                   // [16][68] f32 view

    const char* wsb = (const char*)ws;

    // one-time: gate slabs ki2,ki3 global -> LDS (8192 x 16B)
    {
        const float4* src = (const float4*)(wsb + WP_OFF + 2 * 65536);
        float4* dst = (float4*)slab23;
        for (int i = tid; i < 8192; i += 512) dst[i] = src[i];
    }

    // init both xh buffers: a(0)=0 | z0 | h0 | pad 0
    for (int idx = tid; idx < 2 * 16 * 320; idx += 512) {
        int b = idx / (16 * 320);
        int rem = idx % (16 * 320);
        int r = rem / 320, col = rem % 320;
        float v;
        if (col >= 8 && col < 40)        v = z0[col - 8];
        else if (col >= 40 && col < 296) v = h0[col - 40];
        else                             v = 0.0f;
        xh[b][r][col] = (__bf16)v;
    }
    if (tid < 128)   // a(t=0)
        xh[0][tid >> 3][tid & 7] =
            (__bf16)A[((size_t)(n0 + (tid >> 3)) * T_LEN + 0) * 8 + (tid & 7)];

    // ---- resident weights (per-lane, compile-time indexed throughout) ----
    bf16x8 r0[4][2], r1[4][2];   // gate ki0, ki1 : ct = g*16 + 2w + j
    #pragma unroll
    for (int g = 0; g < 4; ++g)
        #pragma unroll
        for (int j = 0; j < 2; ++j) {
            const size_t cto = (size_t)(g * 16 + 2 * w + j) * 1024 + (size_t)lane * 16;
            r0[g][j] = *(const bf16x8*)(wsb + WP_OFF + cto);
            r1[g][j] = *(const bf16x8*)(wsb + WP_OFF + 65536 + cto);
        }
    bf16x8 w1f[8];               // W1 ct = w
    #pragma unroll
    for (int k = 0; k < 8; ++k)
        w1f[k] = *(const bf16x8*)(wsb + W1P_OFF + ((size_t)(w * 8 + k) * 64 + lane) * 16);

    // biases & recurrent state
    float gb[4][2];
    #pragma unroll
    for (int g = 0; g < 4; ++g)
        #pragma unroll
        for (int j = 0; j < 2; ++j) {
            int unit = 32 * w + 16 * j + lrow;
            gb[g][j] = bih[g * 256 + unit] + bhh[g * 256 + unit];
        }
    float u1b = b1[w * 16 + lrow];
    float u2b = b2[w * 16 + lrow];
    float zzb = (w < 4) ? bz[w * 16 + lrow] : 0.0f;
    float cst[2][4];
    #pragma unroll
    for (int j = 0; j < 2; ++j) {
        float cv = c0[32 * w + 16 * j + lrow];
        #pragma unroll
        for (int r = 0; r < 4; ++r) cst[j][r] = cv;
    }

    __syncthreads();

    // helper macros (all compile-time indices)
    #define GLOAD(BUF, KI) do {                                                   \
        _Pragma("unroll")                                                         \
        for (int g_ = 0; g_ < 4; ++g_)                                            \
            _Pragma("unroll")                                                     \
            for (int j_ = 0; j_ < 2; ++j_)                                        \
                BUF[g_][j_] = *(const bf16x8*)(wsb + WP_OFF + (KI) * 65536 +      \
                    ((size_t)(g_ * 16 + 2 * w + j_) * 1024 + (size_t)lane * 16)); \
    } while (0)
    #define GMFMA(KI, BUF) do {                                                   \
        bf16x8 af_ = *(const bf16x8*)&xh[cb][lrow][(KI) * 32 + quad * 8];         \
        _Pragma("unroll")                                                         \
        for (int g_ = 0; g_ < 4; ++g_)                                            \
            _Pragma("unroll")                                                     \
            for (int j_ = 0; j_ < 2; ++j_)                                        \
                acc[g_][j_] = __builtin_amdgcn_mfma_f32_16x16x32_bf16(            \
                    af_, BUF[g_][j_], acc[g_][j_], 0, 0, 0);                      \
    } while (0)
    #define GMFMA_LDS(KI) do {                                                    \
        bf16x8 af_ = *(const bf16x8*)&xh[cb][lrow][(KI) * 32 + quad * 8];         \
        _Pragma("unroll")                                                         \
        for (int g_ = 0; g_ < 4; ++g_)                                            \
            _Pragma("unroll")                                                     \
            for (int j_ = 0; j_ < 2; ++j_) {                                      \
                bf16x8 b_ = *(const bf16x8*)&slab23[(KI) - 2]                     \
                    [g_ * 8192 + w * 1024 + j_ * 512 + lane * 8];                 \
                acc[g_][j_] = __builtin_amdgcn_mfma_f32_16x16x32_bf16(            \
                    af_, b_, acc[g_][j_], 0, 0, 0);                               \
            }                                                                     \
    } while (0)

    for (int t = 0; t < T_LEN; ++t) {
        const int cb = t & 1;        // X_t
        const int nb = cb ^ 1;       // X_{t+1}

        // per-step activations (values used late; loads overlap gates)
        float eps_cur = eps[((size_t)(n0 + (tid >> 5)) * T_LEN + t) * 32 + (tid & 31)];
        float a_nxt = 0.0f;
        if (t + 1 < T_LEN && tid < 128)
            a_nxt = A[((size_t)(n0 + (tid >> 3)) * T_LEN + (t + 1)) * 8 + (tid & 7)];

        // ---- gates: resident ki0,1 + LDS ki2,3 + streamed ki4..9 ----
        bf16x8 bA[4][2], bB[4][2];
        GLOAD(bA, 4);
        GLOAD(bB, 5);

        floatx4 acc[4][2];
        #pragma unroll
        for (int g = 0; g < 4; ++g)
            #pragma unroll
            for (int j = 0; j < 2; ++j)
                acc[g][j] = (floatx4){gb[g][j], gb[g][j], gb[g][j], gb[g][j]};

        GMFMA(0, r0);
        GMFMA(1, r1);
        GMFMA_LDS(2);
        GMFMA_LDS(3);
        GMFMA(4, bA);  GLOAD(bA, 6);
        GMFMA(5, bB);  GLOAD(bB, 7);
        GMFMA(6, bA);  GLOAD(bA, 8);
        GMFMA(7, bB);  GLOAD(bB, 9);
        GMFMA(8, bA);
        GMFMA(9, bB);

        // ---- LSTM cell (own acc only) -> h_{t+1} into X_{t+1}
        #pragma unroll
        for (int j = 0; j < 2; ++j)
            #pragma unroll
            for (int r = 0; r < 4; ++r) {
                float iv = fsigmoid(acc[0][j][r]);
                float fv = fsigmoid(acc[1][j][r]);
                float gv = ftanh(acc[2][j][r]);
                float ov = fsigmoid(acc[3][j][r]);
                float cn = fv * cst[j][r] + iv * gv;
                cst[j][r] = cn;
                xh[nb][quad * 4 + r][40 + 32 * w + 16 * j + lrow] = (__bf16)(ov * ftanh(cn));
            }
        if (t + 1 < T_LEN && tid < 128)
            xh[nb][tid >> 3][tid & 7] = (__bf16)a_nxt;
        __syncthreads();   // B2: h_{t+1} + a_{t+1} staged

        // ---- u1 = relu(h @ W1^T + b1): all 8 waves, ct=w, W1 resident
        {
            floatx4 a1 = (floatx4){u1b, u1b, u1b, u1b};
            #pragma unroll
            for (int ki = 0; ki < 8; ++ki) {
                bf16x8 af = *(const bf16x8*)&xh[nb][lrow][40 + ki * 32 + quad * 8];
                a1 = __builtin_amdgcn_mfma_f32_16x16x32_bf16(af, w1f[ki], a1, 0, 0, 0);
            }
            #pragma unroll
            for (int r = 0; r < 4; ++r)
                u1s[quad * 4 + r][w * 16 + lrow] = (__bf16)fmaxf(a1[r], 0.0f);
        }
        __syncthreads();   // B3: u1s ready

        // ---- u2 = relu(u1 @ W2^T + b2): W2 streamed (issued here, used now;
        //      latency overlapped with u1s ds_reads), Wz streamed for B5 use.
        {
            bf16x8 w2f[4];
            #pragma unroll
            for (int k = 0; k < 4; ++k)
                w2f[k] = *(const bf16x8*)(wsb + W2P_OFF + ((size_t)(w * 4 + k) * 64 + lane) * 16);
            bf16x8 wzf[4];
            if (w < 4) {
                #pragma unroll
                for (int k = 0; k < 4; ++k)
                    wzf[k] = *(const bf16x8*)(wsb + WZP_OFF + ((size_t)(w * 4 + k) * 64 + lane) * 16);
            }
            floatx4 a2 = (floatx4){u2b, u2b, u2b, u2b};
            #pragma unroll
            for (int ki = 0; ki < 4; ++ki) {
                bf16x8 af = *(const bf16x8*)&u1s[lrow][ki * 32 + quad * 8];
                a2 = __builtin_amdgcn_mfma_f32_16x16x32_bf16(af, w2f[ki], a2, 0, 0, 0);
            }
            #pragma unroll
            for (int r = 0; r < 4; ++r)
                u2s[quad * 4 + r][w * 16 + lrow] = (__bf16)fmaxf(a2[r], 0.0f);
            __syncthreads();   // B4: u2s ready (u1s free for zz overlay)

            // ---- zz = u2 @ Wz^T + bz: waves 0..3 (loc ct 0,1; raw ct 2,3)
            if (w < 4) {
                floatx4 a3 = (floatx4){zzb, zzb, zzb, zzb};
                #pragma unroll
                for (int ki = 0; ki < 4; ++ki) {
                    bf16x8 af = *(const bf16x8*)&u2s[lrow][ki * 32 + quad * 8];
                    a3 = __builtin_amdgcn_mfma_f32_16x16x32_bf16(af, wzf[ki], a3, 0, 0, 0);
                }
                #pragma unroll
                for (int r = 0; r < 4; ++r)
                    zzf[(quad * 4 + r) * 68 + w * 16 + lrow] = a3[r];
            }
        }
        __syncthreads();   // B5: zz ready

        // ---- z = loc + softplus(raw)*eps -> X_{t+1}.z + out
        {
            int r = tid >> 5, c = tid & 31;
            float loc = zzf[r * 68 + c];
            float raw = zzf[r * 68 + c + 32];
            float sp  = (raw > 20.0f)
                      ? raw
                      : 0.6931471805599453f *
                        LOG2F(1.0f + EXP2F(1.4426950408889634f * raw));
            float zv  = loc + sp * eps_cur;
            xh[nb][r][8 + c] = (__bf16)zv;
            out[((size_t)(n0 + r) * T_LEN + t) * 32 + c] = zv;
        }
        __syncthreads();   // B1: X_{t+1} complete for next step
    }
    #undef GLOAD
    #undef GMFMA
    #undef GMFMA_LDS
}

// ---------------- fallback: proven R4 VALU kernel (f32 hard-coded) --------
struct SM {
    float zx[4][40]; float h[4][256]; float u1[4][128]; float u2[4][128]; float zz[4][64];
};

__global__ __launch_bounds__(256) void seq_valu(
    const float* __restrict__ A, const float* __restrict__ eps,
    const float* __restrict__ z0, const float* __restrict__ h0, const float* __restrict__ c0,
    const float* __restrict__ Wih, const float* __restrict__ Whh,
    const float* __restrict__ bih, const float* __restrict__ bhh,
    const float* __restrict__ W1, const float* __restrict__ b1,
    const float* __restrict__ W2, const float* __restrict__ b2,
    const float* __restrict__ Wz, const float* __restrict__ bz, float* __restrict__ out)
{
    __shared__ SM sm;
    const int tid = threadIdx.x;
    const int n0  = blockIdx.x * 4;
    if (tid < 128) { int rr = tid >> 5, cc = tid & 31; sm.zx[rr][8 + cc] = z0[cc]; }
    for (int i = tid; i < 4 * 256; i += 256) sm.h[i >> 8][i & 255] = h0[i & 255];
    float c[4];
    #pragma unroll
    for (int rr = 0; rr < 4; ++rr) c[rr] = c0[tid];
    float gbias[4];
    #pragma unroll
    for (int g = 0; g < 4; ++g) gbias[g] = bih[g * 256 + tid] + bhh[g * 256 + tid];

    for (int t = 0; t < T_LEN; ++t) {
        if (tid < 32) { int rr = tid >> 3, cc = tid & 7;
            sm.zx[rr][cc] = A[((size_t)(n0 + rr) * T_LEN + t) * 8 + cc]; }
        __syncthreads();
        float acc[4][4];
        #pragma unroll
        for (int g = 0; g < 4; ++g)
            #pragma unroll
            for (int rr = 0; rr < 4; ++rr) acc[g][rr] = gbias[g];
        for (int k = 0; k < 40; ++k) {
            float xv[4];
            #pragma unroll
            for (int rr = 0; rr < 4; ++rr) xv[rr] = sm.zx[rr][k];
            #pragma unroll
            for (int g = 0; g < 4; ++g) {
                float w = Wih[(size_t)(g * 256 + tid) * 40 + k];
                #pragma unroll
                for (int rr = 0; rr < 4; ++rr) acc[g][rr] += w * xv[rr];
            }
        }
        for (int k = 0; k < 256; ++k) {
            float hv[4];
            #pragma unroll
            for (int rr = 0; rr < 4; ++rr) hv[rr] = sm.h[rr][k];
            #pragma unroll
            for (int g = 0; g < 4; ++g) {
                float w = Whh[(size_t)(g * 256 + tid) * 256 + k];
                #pragma unroll
                for (int rr = 0; rr < 4; ++rr) acc[g][rr] += w * hv[rr];
            }
        }
        __syncthreads();
        #pragma unroll
        for (int rr = 0; rr < 4; ++rr) {
            float iv = 1.0f / (1.0f + expf(-acc[0][rr]));
            float fv = 1.0f / (1.0f + expf(-acc[1][rr]));
            float gv = tanhf(acc[2][rr]);
            float ov = 1.0f / (1.0f + expf(-acc[3][rr]));
            float cn = fv * c[rr] + iv * gv;
            c[rr] = cn;
            sm.h[rr][tid] = ov * tanhf(cn);
        }
        __syncthreads();
        { int col = tid & 127, rb = (tid >> 7) * 2;
          float a0 = b1[col], a1 = a0;
          for (int k = 0; k < 256; ++k) { float w = W1[(size_t)col * 256 + k];
              a0 += w * sm.h[rb][k]; a1 += w * sm.h[rb + 1][k]; }
          sm.u1[rb][col] = fmaxf(a0, 0.0f); sm.u1[rb + 1][col] = fmaxf(a1, 0.0f); }
        __syncthreads();
        { int col = tid & 127, rb = (tid >> 7) * 2;
          float a0 = b2[col], a1 = a0;
          for (int k = 0; k < 128; ++k) { float w = W2[(size_t)col * 128 + k];
              a0 += w * sm.u1[rb][k]; a1 += w * sm.u1[rb + 1][k]; }
          sm.u2[rb][col] = fmaxf(a0, 0.0f); sm.u2[rb + 1][col] = fmaxf(a1, 0.0f); }
        __syncthreads();
        { int rr = tid >> 6, col = tid & 63;
          float a0 = bz[col];
          for (int k = 0; k < 128; ++k) a0 += Wz[(size_t)col * 128 + k] * sm.u2[rr][k];
          sm.zz[rr][col] = a0; }
        __syncthreads();
        if (tid < 128) {
            int rr = tid >> 5, cc = tid & 31;
            float loc = sm.zz[rr][cc], raw = sm.zz[rr][cc + 32];
            float sp  = (raw > 20.0f) ? raw : log1pf(expf(raw));
            float ev  = eps[((size_t)(n0 + rr) * T_LEN + t) * 32 + cc];
            float zv  = loc + sp * ev;
            sm.zx[rr][8 + cc] = zv;
            out[((size_t)(n0 + rr) * T_LEN + t) * 32 + cc] = zv;
        }
        __syncthreads();
    }
}

extern "C" void kernel_launch(void* const* d_in, const int* in_sizes, int n_in,
                              void* d_out, int out_size, void* d_ws, size_t ws_size,
                              hipStream_t stream)
{
    const float* A   = (const float*)d_in[0];
    const float* eps = (const float*)d_in[1];
    const float* z0  = (const float*)d_in[2];
    const float* h0  = (const float*)d_in[3];
    const float* c0  = (const float*)d_in[4];
    const float* Wih = (const float*)d_in[5];
    const float* Whh = (const float*)d_in[6];
    const float* bih = (const float*)d_in[7];
    const float* bhh = (const float*)d_in[8];
    const float* W1  = (const float*)d_in[9];
    const float* b1  = (const float*)d_in[10];
    const float* W2  = (const float*)d_in[11];
    const float* b2  = (const float*)d_in[12];
    const float* Wz  = (const float*)d_in[13];
    const float* bz  = (const float*)d_in[14];
    float* out = (float*)d_out;

    if (ws_size >= WS_NEEDED) {
        prep_kernel<<<188, 256, 0, stream>>>(Wih, Whh, W1, W2, Wz, (unsigned char*)d_ws);
        seq_mfma<<<64, 512, 0, stream>>>(A, eps, z0, h0, c0,
                                         bih, bhh, b1, b2, bz,
                                         (const unsigned char*)d_ws, out);
    } else {
        seq_valu<<<256, 256, 0, stream>>>(A, eps, z0, h0, c0, Wih, Whh, bih, bhh,
                                          W1, b1, W2, b2, Wz, bz, out);
    }
}